// Round 1
// baseline (99.063 us; speedup 1.0000x reference)
//
#include <hip/hip_runtime.h>
#include <hip/hip_bf16.h>

// CapsuleNet dynamic routing, fused per-sample. fp32 I/O:
// x: f32 [8192, 32, 8], W: f32 [32, 8, 256], out: f32 [8192, 16, 16].
// One block = 2 samples; thread t = (nc = t>>4, dc = t&15) owns column k = t.
// r15: x reads are WAVE-UNIFORM s_loads of pre-converted f16 (zero VALU/DS
// cost). uh stored NORMAL-order packed f16 (s0,s1) v2h[32]; butterfly uses
// 32-bit cndmask selects (both samples per select) + DPP transports.
// r16 (this round): DS-pipe relief —
//  * c.uh reads as ds_read_b128 (8/round instead of 32 b32): rows are 160 B
//    (16B-aligned); wave's 4 nc-rows sit at disjoint bank quads {0,8,16,24}
//    -> conflict-free 4-address broadcasts.
//  * b_lds transposed to [S][32 ic][20 nc]: softmax row-read becomes ONE
//    ds_read_b128 (80*ic+16*q bytes, aligned); butterfly writes land at
//    bank (20*dc+nc)%32 -> uniform 2-way (free).
//  * occupancy 6 -> 8 blocks/CU (__launch_bounds__(256,8); VGPR=44 <= 64).

#define S 2

typedef float    v2f __attribute__((ext_vector_type(2)));
typedef float    v4f __attribute__((ext_vector_type(4)));
typedef _Float16 v2h __attribute__((ext_vector_type(2)));
typedef _Float16 v8h __attribute__((ext_vector_type(8)));

__device__ __forceinline__ v2h pack2h(float a, float b) {
  return __builtin_bit_cast(v2h, __builtin_amdgcn_cvt_pkrtz(a, b));  // v_cvt_pkrtz_f16_f32
}

// DPP cross-lane: value of `x` from lane (lane ^ k) within a 16-lane row.
// 0xB1 = quad_perm[1,0,3,2] (xor1)  0x4E = quad_perm[2,3,0,1] (xor2)
// 0x128 = row_ror:8 (xor8)  0x141 = row_half_mirror  0x140 = row_mirror
template <int CTRL>
__device__ __forceinline__ float dppf(float x) {
  return __builtin_bit_cast(float,
      __builtin_amdgcn_update_dpp(0, __builtin_bit_cast(int, x), CTRL, 0xF, 0xF, true));
}
template <int CTRL>
__device__ __forceinline__ v2h dpph(v2h v) {  // both samples in one DPP
  return __builtin_bit_cast(v2h,
      __builtin_amdgcn_update_dpp(0, __builtin_bit_cast(int, v), CTRL, 0xF, 0xF, true));
}
// Masked DPP keeping `old` on disabled banks (bound_ctrl=false: keep old).
template <int CTRL, int BANK>
__device__ __forceinline__ int dpp_old_i(int old, int x) {
  return __builtin_amdgcn_update_dpp(old, x, CTRL, 0xF, BANK, false);
}
// Deliver partner(lane^4)'s value of s to every lane (validated r10/r13):
// banks 0,2 (lanes 0-3,8-11): from lane+4 via row_shl:4 (0x104);
// banks 1,3 (lanes 4-7,12-15): from lane-4 via row_shr:4 (0x114).
__device__ __forceinline__ v2h xor4t_h(v2h s) {
  int si = __builtin_bit_cast(int, s);
  int ya = dpp_old_i<0x104, 0x5>(0, si);
  return __builtin_bit_cast(v2h, dpp_old_i<0x114, 0xA>(ya, si));
}

#if __has_builtin(__builtin_amdgcn_fdot2)
__device__ __forceinline__ float dot2(v2h a, v2h b, float c) {
  return __builtin_amdgcn_fdot2(a, b, c, false);  // v_dot2_f32_f16
}
#else
__device__ __forceinline__ float dot2(v2h a, v2h b, float c) {
  return fmaf((float)a.x, (float)b.x, fmaf((float)a.y, (float)b.y, c));
}
#endif

// Fused prep: blocks 0..255: W[ic][id][k](f32) -> Wth[ic][k][id](f16), NO
// permute; blocks 256..1279: x (f32) -> xh (f16), 8 elems/thread.
__global__ __launch_bounds__(256) void prep_kernel(const float* __restrict__ W,
                                                   const float* __restrict__ x,
                                                   _Float16* __restrict__ Wth,
                                                   _Float16* __restrict__ xh) {
  int bid = blockIdx.x;
  if (bid < 256) {
    int o  = bid * 256 + threadIdx.x;
    int ic = o >> 11;
    int k  = (o >> 3) & 255;
    int id = o & 7;
    Wth[o] = (_Float16)W[(ic * 8 + id) * 256 + k];
  } else {
    int tid = (bid - 256) * 256 + threadIdx.x;
    const float4* xp = (const float4*)x + tid * 2;
    float4 f0 = xp[0], f1 = xp[1];
    v2h h0 = {(_Float16)f0.x, (_Float16)f0.y};
    v2h h1 = {(_Float16)f0.z, (_Float16)f0.w};
    v2h h2 = {(_Float16)f1.x, (_Float16)f1.y};
    v2h h3 = {(_Float16)f1.z, (_Float16)f1.w};
    uint4 o;
    o.x = __builtin_bit_cast(unsigned, h0);
    o.y = __builtin_bit_cast(unsigned, h1);
    o.z = __builtin_bit_cast(unsigned, h2);
    o.w = __builtin_bit_cast(unsigned, h3);
    ((uint4*)xh)[tid] = o;
  }
}

// squash over the 16 dc lanes, both samples at once; DPP-only reduction (f32).
__device__ __forceinline__ v2f squash2(v2f o) {
  v2f s2 = o * o;
  s2.x += dppf<0xB1>(s2.x);   s2.y += dppf<0xB1>(s2.y);    // + lane^1
  s2.x += dppf<0x4E>(s2.x);   s2.y += dppf<0x4E>(s2.y);    // + lane^2
  s2.x += dppf<0x141>(s2.x);  s2.y += dppf<0x141>(s2.y);   // + lane^7
  s2.x += dppf<0x140>(s2.x);  s2.y += dppf<0x140>(s2.y);   // + lane^15
  s2 += (v2f){1e-7f, 1e-7f};
  v2f sc;
  sc.x = s2.x * __builtin_amdgcn_rsqf(s2.x) * __builtin_amdgcn_rcpf(1.f + s2.x);
  sc.y = s2.y * __builtin_amdgcn_rsqf(s2.y) * __builtin_amdgcn_rcpf(1.f + s2.y);
  return o * sc;  // sqrt(s2)/(1+s2) * o
}

// Butterfly transpose-reduction on NORMAL-order packed-f16 uh (selects are
// single 32-bit cndmasks moving both samples). Lane dc lands b[icb+dc][nc]
// (f32, transposed layout: bp* pre-offset to &b_lds[s][dc][nc], row stride
// 20 floats; icb*20 is a compile-time ds offset immediate).
// Levels 8/2/1 via DPP xor; level 4 via the masked dual-DPP transport.
template <bool ASSIGN>
__device__ __forceinline__ void b_update2(v2h vh, const v2h* uh, int dc,
                                          float* bp0, float* bp1) {
#pragma unroll
  for (int icb = 0; icb < 32; icb += 16) {
    v2h a[16];
#pragma unroll
    for (int j = 0; j < 16; ++j) a[j] = vh * uh[icb + j];  // pk_mul_f16
    v2h b8[8];
    const bool u8 = (dc & 8) != 0;
#pragma unroll
    for (int j = 0; j < 8; ++j) {
      v2h send = u8 ? a[j] : a[j + 8];
      v2h recv = dpph<0x128>(send);              // partner(lane^8)'s send
      b8[j] = (u8 ? a[j + 8] : a[j]) + recv;
    }
    v2h c4[4];
    const bool u4 = (dc & 4) != 0;
#pragma unroll
    for (int j = 0; j < 4; ++j) {
      v2h send = u4 ? b8[j] : b8[j + 4];
      v2h recv = xor4t_h(send);                  // partner(lane^4)'s send
      c4[j] = (u4 ? b8[j + 4] : b8[j]) + recv;
    }
    v2h d2[2];
    const bool u2 = (dc & 2) != 0;
#pragma unroll
    for (int j = 0; j < 2; ++j) {
      v2h send = u2 ? c4[j] : c4[j + 2];
      v2h recv = dpph<0x4E>(send);               // partner(lane^2)'s send
      d2[j] = (u2 ? c4[j + 2] : c4[j]) + recv;
    }
    const bool u1 = (dc & 1) != 0;
    v2h send = u1 ? d2[0] : d2[1];
    v2h recv = dpph<0xB1>(send);                 // partner(lane^1)'s send
    v2h e = (u1 ? d2[1] : d2[0]) + recv;
    float e0 = (float)e.x, e1 = (float)e.y;
    if (ASSIGN) { bp0[icb * 20] = e0;  bp1[icb * 20] = e1; }
    else        { bp0[icb * 20] += e0; bp1[icb * 20] += e1; }
  }
}

#define CSTRIDE 40  // v2h per c-row: 160 B rows, 16B-aligned; 4 nc-rows/wave
                    // start at bank-dword {0,8,16,24} -> b128 broadcast clean

__global__ __launch_bounds__(256, 8) void caps_kernel(const _Float16* __restrict__ xh,
                                                      const uint4* __restrict__ Wt4,
                                                      float* __restrict__ out) {
  const int t  = threadIdx.x;
  const int nc = t >> 4;
  const int dc = t & 15;
  const int s0 = blockIdx.x * S;

  // b transposed: [sample][ic 0..31][nc 0..15 padded to 20].
  // softmax reads b[ss][ic][4q..4q+3] as ONE ds_read_b128 (16B-aligned).
  __shared__ __align__(16) float b_lds[S][32][20];
  __shared__ __align__(16) v2h c16h[16 * CSTRIDE];  // c[n][ic] f16 pairs

  v2h uh[32];                          // packed (s0,s1), normal order
  v2f o2 = (v2f){0.f, 0.f};

  // ---- u_hat: wave-uniform x (s_load, free) + one b128 W load per ic ----
  const v2h* xp0 = (const v2h*)(xh + (s0 + 0) * 256);  // block-uniform -> s_load
  const v2h* xp1 = (const v2h*)(xh + (s0 + 1) * 256);
#pragma unroll
  for (int ic = 0; ic < 32; ++ic) {
    uint4 wv = Wt4[ic * 256 + t];  // 8 f16 weights, one coalesced dwordx4
    v2h w0 = __builtin_bit_cast(v2h, wv.x);
    v2h w1 = __builtin_bit_cast(v2h, wv.y);
    v2h w2 = __builtin_bit_cast(v2h, wv.z);
    v2h w3 = __builtin_bit_cast(v2h, wv.w);
    float a0 = dot2(xp0[ic * 4 + 3], w3,
               dot2(xp0[ic * 4 + 2], w2,
               dot2(xp0[ic * 4 + 1], w1,
               dot2(xp0[ic * 4 + 0], w0, 0.f))));
    float a1 = dot2(xp1[ic * 4 + 3], w3,
               dot2(xp1[ic * 4 + 2], w2,
               dot2(xp1[ic * 4 + 1], w1,
               dot2(xp1[ic * 4 + 0], w0, 0.f))));
    o2 += (v2f){a0, a1};
    uh[ic] = pack2h(a0, a1);  // 1 inst pack to f16 pair
  }

  float* bp0 = &b_lds[0][dc][nc];  // transposed-target base for this thread
  float* bp1 = &b_lds[1][dc][nc];

  // ---- routing round 0: b = 0 => c = 1/16 ----
  {
    v2f v = squash2(o2 * (v2f){0.0625f, 0.0625f});
    v2h vh = pack2h(v.x, v.y);
    b_update2<true>(vh, uh, dc, bp0, bp1);
  }
  __syncthreads();

  // ---- rounds 1, 2 ----
#pragma unroll
  for (int r = 1; r < 3; ++r) {
    {  // distributed softmax over nc: all 256 threads. thread -> (s, ic, quarter)
      const int ss  = t >> 7;         // sample
      const int icc = (t >> 2) & 31;  // column (ic)
      const int q   = t & 3;          // nc rows 4q..4q+3
      // no max-subtraction: |b| bounded far below exp overflow; shift-invariant.
      const v4f bq = *(const v4f*)&b_lds[ss][icc][4 * q];  // one ds_read_b128
      float e0 = __expf(bq.x);
      float e1 = __expf(bq.y);
      float e2 = __expf(bq.z);
      float e3 = __expf(bq.w);
      float ps = (e0 + e1) + (e2 + e3);
      ps += dppf<0xB1>(ps);  // + lane^1 (quad)
      ps += dppf<0x4E>(ps);  // + lane^2 (quad) -> full 16-row sum
      float inv = __builtin_amdgcn_rcpf(ps);
      _Float16* cw = (_Float16*)c16h + ss;  // component ss of each pair
      cw[((4 * q + 0) * CSTRIDE + icc) * 2] = (_Float16)(e0 * inv);
      cw[((4 * q + 1) * CSTRIDE + icc) * 2] = (_Float16)(e1 * inv);
      cw[((4 * q + 2) * CSTRIDE + icc) * 2] = (_Float16)(e2 * inv);
      cw[((4 * q + 3) * CSTRIDE + icc) * 2] = (_Float16)(e3 * inv);
    }
    __syncthreads();

    // c.uh: 8 ds_read_b128 broadcasts (4 ic-pairs per b128; cr[blk] = ic
    // 4blk..4blk+3, cr[blk+4] = ic 16+4blk..). Disjoint bank quads per wave.
    const v8h* cr = (const v8h*)(c16h + nc * CSTRIDE);
    v2h oh = (v2h){(_Float16)0.f, (_Float16)0.f};
#pragma unroll
    for (int blk = 0; blk < 4; ++blk) {
      uint4 ua = __builtin_bit_cast(uint4, cr[blk]);      // ic 4blk..4blk+3
      uint4 ub = __builtin_bit_cast(uint4, cr[blk + 4]);  // ic 16+4blk..
      oh = __builtin_elementwise_fma(__builtin_bit_cast(v2h, ua.x), uh[4 * blk + 0], oh);
      oh = __builtin_elementwise_fma(__builtin_bit_cast(v2h, ua.y), uh[4 * blk + 1], oh);
      oh = __builtin_elementwise_fma(__builtin_bit_cast(v2h, ua.z), uh[4 * blk + 2], oh);
      oh = __builtin_elementwise_fma(__builtin_bit_cast(v2h, ua.w), uh[4 * blk + 3], oh);
      oh = __builtin_elementwise_fma(__builtin_bit_cast(v2h, ub.x), uh[16 + 4 * blk + 0], oh);
      oh = __builtin_elementwise_fma(__builtin_bit_cast(v2h, ub.y), uh[16 + 4 * blk + 1], oh);
      oh = __builtin_elementwise_fma(__builtin_bit_cast(v2h, ub.z), uh[16 + 4 * blk + 2], oh);
      oh = __builtin_elementwise_fma(__builtin_bit_cast(v2h, ub.w), uh[16 + 4 * blk + 3], oh);
    }
    v2f o = (v2f){(float)oh.x, (float)oh.y};
    v2f v = squash2(o);
    if (r == 2) {
      out[(s0 + 0) * 256 + t] = v.x;
      out[(s0 + 1) * 256 + t] = v.y;
    } else {
      v2h vh = pack2h(v.x, v.y);
      b_update2<false>(vh, uh, dc, bp0, bp1);
      __syncthreads();  // b complete before round-2 softmax; c overwrite safe
    }
  }
}

extern "C" void kernel_launch(void* const* d_in, const int* in_sizes, int n_in,
                              void* d_out, int out_size, void* d_ws, size_t ws_size,
                              hipStream_t stream) {
  const float* x = (const float*)d_in[0];
  const float* W = (const float*)d_in[1];
  _Float16* Wth = (_Float16*)d_ws;           // 128 KB: f16 W-transpose
  _Float16* xh  = (_Float16*)d_ws + 65536;   // 4 MB: f16 x

  prep_kernel<<<1280, 256, 0, stream>>>(W, x, Wth, xh);
  caps_kernel<<<8192 / S, 256, 0, stream>>>(xh, (const uint4*)Wth, (float*)d_out);
}

// Round 3
// 92.303 us; speedup vs baseline: 1.0732x; 1.0732x over previous
//
#include <hip/hip_runtime.h>
#include <hip/hip_bf16.h>

// CapsuleNet dynamic routing, fused per-sample. fp32 I/O:
// x: f32 [8192, 32, 8], W: f32 [32, 8, 256], out: f32 [8192, 16, 16].
// One block = 2 samples; thread t = (nc = t>>4, dc = t&15) owns column k = t.
// r15: x reads are WAVE-UNIFORM s_loads of pre-converted f16 (zero VALU/DS
// cost). uh stored NORMAL-order packed f16 (s0,s1) v2h[32]; butterfly uses
// 32-bit cndmask selects (both samples per select) + DPP transports.
// r16: c.uh reads as ds_read_b128 broadcasts; b_lds transposed [S][32][20]
// so softmax row-read is ONE ds_read_b128; butterfly b-writes 2-way (free).
// r17: REVERT (256,8) -> (256,6): the 8-block bound cut VGPR to 32 ->
//   uh[32] spilled to scratch (WRITE_SIZE 77.8 MB vs 8 MB output).
//   CSTRIDE 40 -> 44: softmax c-writes 4-way -> 2-way banks (free).
// r18 (this round): identical resubmit — r17 never ran (container
//   acquisition failed twice; no kernel-side signal).

#define S 2

typedef float    v2f __attribute__((ext_vector_type(2)));
typedef float    v4f __attribute__((ext_vector_type(4)));
typedef _Float16 v2h __attribute__((ext_vector_type(2)));
typedef _Float16 v8h __attribute__((ext_vector_type(8)));

__device__ __forceinline__ v2h pack2h(float a, float b) {
  return __builtin_bit_cast(v2h, __builtin_amdgcn_cvt_pkrtz(a, b));  // v_cvt_pkrtz_f16_f32
}

// DPP cross-lane: value of `x` from lane (lane ^ k) within a 16-lane row.
// 0xB1 = quad_perm[1,0,3,2] (xor1)  0x4E = quad_perm[2,3,0,1] (xor2)
// 0x128 = row_ror:8 (xor8)  0x141 = row_half_mirror  0x140 = row_mirror
template <int CTRL>
__device__ __forceinline__ float dppf(float x) {
  return __builtin_bit_cast(float,
      __builtin_amdgcn_update_dpp(0, __builtin_bit_cast(int, x), CTRL, 0xF, 0xF, true));
}
template <int CTRL>
__device__ __forceinline__ v2h dpph(v2h v) {  // both samples in one DPP
  return __builtin_bit_cast(v2h,
      __builtin_amdgcn_update_dpp(0, __builtin_bit_cast(int, v), CTRL, 0xF, 0xF, true));
}
// Masked DPP keeping `old` on disabled banks (bound_ctrl=false: keep old).
template <int CTRL, int BANK>
__device__ __forceinline__ int dpp_old_i(int old, int x) {
  return __builtin_amdgcn_update_dpp(old, x, CTRL, 0xF, BANK, false);
}
// Deliver partner(lane^4)'s value of s to every lane (validated r10/r13):
// banks 0,2 (lanes 0-3,8-11): from lane+4 via row_shl:4 (0x104);
// banks 1,3 (lanes 4-7,12-15): from lane-4 via row_shr:4 (0x114).
__device__ __forceinline__ v2h xor4t_h(v2h s) {
  int si = __builtin_bit_cast(int, s);
  int ya = dpp_old_i<0x104, 0x5>(0, si);
  return __builtin_bit_cast(v2h, dpp_old_i<0x114, 0xA>(ya, si));
}

#if __has_builtin(__builtin_amdgcn_fdot2)
__device__ __forceinline__ float dot2(v2h a, v2h b, float c) {
  return __builtin_amdgcn_fdot2(a, b, c, false);  // v_dot2_f32_f16
}
#else
__device__ __forceinline__ float dot2(v2h a, v2h b, float c) {
  return fmaf((float)a.x, (float)b.x, fmaf((float)a.y, (float)b.y, c));
}
#endif

// Fused prep: blocks 0..255: W[ic][id][k](f32) -> Wth[ic][k][id](f16), NO
// permute; blocks 256..1279: x (f32) -> xh (f16), 8 elems/thread.
__global__ __launch_bounds__(256) void prep_kernel(const float* __restrict__ W,
                                                   const float* __restrict__ x,
                                                   _Float16* __restrict__ Wth,
                                                   _Float16* __restrict__ xh) {
  int bid = blockIdx.x;
  if (bid < 256) {
    int o  = bid * 256 + threadIdx.x;
    int ic = o >> 11;
    int k  = (o >> 3) & 255;
    int id = o & 7;
    Wth[o] = (_Float16)W[(ic * 8 + id) * 256 + k];
  } else {
    int tid = (bid - 256) * 256 + threadIdx.x;
    const float4* xp = (const float4*)x + tid * 2;
    float4 f0 = xp[0], f1 = xp[1];
    v2h h0 = {(_Float16)f0.x, (_Float16)f0.y};
    v2h h1 = {(_Float16)f0.z, (_Float16)f0.w};
    v2h h2 = {(_Float16)f1.x, (_Float16)f1.y};
    v2h h3 = {(_Float16)f1.z, (_Float16)f1.w};
    uint4 o;
    o.x = __builtin_bit_cast(unsigned, h0);
    o.y = __builtin_bit_cast(unsigned, h1);
    o.z = __builtin_bit_cast(unsigned, h2);
    o.w = __builtin_bit_cast(unsigned, h3);
    ((uint4*)xh)[tid] = o;
  }
}

// squash over the 16 dc lanes, both samples at once; DPP-only reduction (f32).
__device__ __forceinline__ v2f squash2(v2f o) {
  v2f s2 = o * o;
  s2.x += dppf<0xB1>(s2.x);   s2.y += dppf<0xB1>(s2.y);    // + lane^1
  s2.x += dppf<0x4E>(s2.x);   s2.y += dppf<0x4E>(s2.y);    // + lane^2
  s2.x += dppf<0x141>(s2.x);  s2.y += dppf<0x141>(s2.y);   // + lane^7
  s2.x += dppf<0x140>(s2.x);  s2.y += dppf<0x140>(s2.y);   // + lane^15
  s2 += (v2f){1e-7f, 1e-7f};
  v2f sc;
  sc.x = s2.x * __builtin_amdgcn_rsqf(s2.x) * __builtin_amdgcn_rcpf(1.f + s2.x);
  sc.y = s2.y * __builtin_amdgcn_rsqf(s2.y) * __builtin_amdgcn_rcpf(1.f + s2.y);
  return o * sc;  // sqrt(s2)/(1+s2) * o
}

// Butterfly transpose-reduction on NORMAL-order packed-f16 uh (selects are
// single 32-bit cndmasks moving both samples). Lane dc lands b[icb+dc][nc]
// (f32, transposed layout: bp* pre-offset to &b_lds[s][dc][nc], row stride
// 20 floats; icb*20 is a compile-time ds offset immediate).
// Levels 8/2/1 via DPP xor; level 4 via the masked dual-DPP transport.
template <bool ASSIGN>
__device__ __forceinline__ void b_update2(v2h vh, const v2h* uh, int dc,
                                          float* bp0, float* bp1) {
#pragma unroll
  for (int icb = 0; icb < 32; icb += 16) {
    v2h a[16];
#pragma unroll
    for (int j = 0; j < 16; ++j) a[j] = vh * uh[icb + j];  // pk_mul_f16
    v2h b8[8];
    const bool u8 = (dc & 8) != 0;
#pragma unroll
    for (int j = 0; j < 8; ++j) {
      v2h send = u8 ? a[j] : a[j + 8];
      v2h recv = dpph<0x128>(send);              // partner(lane^8)'s send
      b8[j] = (u8 ? a[j + 8] : a[j]) + recv;
    }
    v2h c4[4];
    const bool u4 = (dc & 4) != 0;
#pragma unroll
    for (int j = 0; j < 4; ++j) {
      v2h send = u4 ? b8[j] : b8[j + 4];
      v2h recv = xor4t_h(send);                  // partner(lane^4)'s send
      c4[j] = (u4 ? b8[j + 4] : b8[j]) + recv;
    }
    v2h d2[2];
    const bool u2 = (dc & 2) != 0;
#pragma unroll
    for (int j = 0; j < 2; ++j) {
      v2h send = u2 ? c4[j] : c4[j + 2];
      v2h recv = dpph<0x4E>(send);               // partner(lane^2)'s send
      d2[j] = (u2 ? c4[j + 2] : c4[j]) + recv;
    }
    const bool u1 = (dc & 1) != 0;
    v2h send = u1 ? d2[0] : d2[1];
    v2h recv = dpph<0xB1>(send);                 // partner(lane^1)'s send
    v2h e = (u1 ? d2[1] : d2[0]) + recv;
    float e0 = (float)e.x, e1 = (float)e.y;
    if (ASSIGN) { bp0[icb * 20] = e0;  bp1[icb * 20] = e1; }
    else        { bp0[icb * 20] += e0; bp1[icb * 20] += e1; }
  }
}

#define CSTRIDE 44  // v2h per c-row: 176 B rows (16B-aligned). Read side: 4
                    // nc-row broadcasts at bank quads {12nc%32}+blk -> disjoint.
                    // Write side: bank (16q+12r+icc)%32 -> 2 lanes/bank (free).

__global__ __launch_bounds__(256, 6) void caps_kernel(const _Float16* __restrict__ xh,
                                                      const uint4* __restrict__ Wt4,
                                                      float* __restrict__ out) {
  const int t  = threadIdx.x;
  const int nc = t >> 4;
  const int dc = t & 15;
  const int s0 = blockIdx.x * S;

  // b transposed: [sample][ic 0..31][nc 0..15 padded to 20].
  // softmax reads b[ss][ic][4q..4q+3] as ONE ds_read_b128 (16B-aligned).
  __shared__ __align__(16) float b_lds[S][32][20];
  __shared__ __align__(16) v2h c16h[16 * CSTRIDE];  // c[n][ic] f16 pairs

  v2h uh[32];                          // packed (s0,s1), normal order
  v2f o2 = (v2f){0.f, 0.f};

  // ---- u_hat: wave-uniform x (s_load, free) + one b128 W load per ic ----
  const v2h* xp0 = (const v2h*)(xh + (s0 + 0) * 256);  // block-uniform -> s_load
  const v2h* xp1 = (const v2h*)(xh + (s0 + 1) * 256);
#pragma unroll
  for (int ic = 0; ic < 32; ++ic) {
    uint4 wv = Wt4[ic * 256 + t];  // 8 f16 weights, one coalesced dwordx4
    v2h w0 = __builtin_bit_cast(v2h, wv.x);
    v2h w1 = __builtin_bit_cast(v2h, wv.y);
    v2h w2 = __builtin_bit_cast(v2h, wv.z);
    v2h w3 = __builtin_bit_cast(v2h, wv.w);
    float a0 = dot2(xp0[ic * 4 + 3], w3,
               dot2(xp0[ic * 4 + 2], w2,
               dot2(xp0[ic * 4 + 1], w1,
               dot2(xp0[ic * 4 + 0], w0, 0.f))));
    float a1 = dot2(xp1[ic * 4 + 3], w3,
               dot2(xp1[ic * 4 + 2], w2,
               dot2(xp1[ic * 4 + 1], w1,
               dot2(xp1[ic * 4 + 0], w0, 0.f))));
    o2 += (v2f){a0, a1};
    uh[ic] = pack2h(a0, a1);  // 1 inst pack to f16 pair
  }

  float* bp0 = &b_lds[0][dc][nc];  // transposed-target base for this thread
  float* bp1 = &b_lds[1][dc][nc];

  // ---- routing round 0: b = 0 => c = 1/16 ----
  {
    v2f v = squash2(o2 * (v2f){0.0625f, 0.0625f});
    v2h vh = pack2h(v.x, v.y);
    b_update2<true>(vh, uh, dc, bp0, bp1);
  }
  __syncthreads();

  // ---- rounds 1, 2 ----
#pragma unroll
  for (int r = 1; r < 3; ++r) {
    {  // distributed softmax over nc: all 256 threads. thread -> (s, ic, quarter)
      const int ss  = t >> 7;         // sample
      const int icc = (t >> 2) & 31;  // column (ic)
      const int q   = t & 3;          // nc rows 4q..4q+3
      // no max-subtraction: |b| bounded far below exp overflow; shift-invariant.
      const v4f bq = *(const v4f*)&b_lds[ss][icc][4 * q];  // one ds_read_b128
      float e0 = __expf(bq.x);
      float e1 = __expf(bq.y);
      float e2 = __expf(bq.z);
      float e3 = __expf(bq.w);
      float ps = (e0 + e1) + (e2 + e3);
      ps += dppf<0xB1>(ps);  // + lane^1 (quad)
      ps += dppf<0x4E>(ps);  // + lane^2 (quad) -> full 16-row sum
      float inv = __builtin_amdgcn_rcpf(ps);
      _Float16* cw = (_Float16*)c16h + ss;  // component ss of each pair
      cw[((4 * q + 0) * CSTRIDE + icc) * 2] = (_Float16)(e0 * inv);
      cw[((4 * q + 1) * CSTRIDE + icc) * 2] = (_Float16)(e1 * inv);
      cw[((4 * q + 2) * CSTRIDE + icc) * 2] = (_Float16)(e2 * inv);
      cw[((4 * q + 3) * CSTRIDE + icc) * 2] = (_Float16)(e3 * inv);
    }
    __syncthreads();

    // c.uh: 8 ds_read_b128 broadcasts (4 ic-pairs per b128; cr[blk] = ic
    // 4blk..4blk+3, cr[blk+4] = ic 16+4blk..). Disjoint bank quads per wave.
    const v8h* cr = (const v8h*)(c16h + nc * CSTRIDE);
    v2h oh = (v2h){(_Float16)0.f, (_Float16)0.f};
#pragma unroll
    for (int blk = 0; blk < 4; ++blk) {
      uint4 ua = __builtin_bit_cast(uint4, cr[blk]);      // ic 4blk..4blk+3
      uint4 ub = __builtin_bit_cast(uint4, cr[blk + 4]);  // ic 16+4blk..
      oh = __builtin_elementwise_fma(__builtin_bit_cast(v2h, ua.x), uh[4 * blk + 0], oh);
      oh = __builtin_elementwise_fma(__builtin_bit_cast(v2h, ua.y), uh[4 * blk + 1], oh);
      oh = __builtin_elementwise_fma(__builtin_bit_cast(v2h, ua.z), uh[4 * blk + 2], oh);
      oh = __builtin_elementwise_fma(__builtin_bit_cast(v2h, ua.w), uh[4 * blk + 3], oh);
      oh = __builtin_elementwise_fma(__builtin_bit_cast(v2h, ub.x), uh[16 + 4 * blk + 0], oh);
      oh = __builtin_elementwise_fma(__builtin_bit_cast(v2h, ub.y), uh[16 + 4 * blk + 1], oh);
      oh = __builtin_elementwise_fma(__builtin_bit_cast(v2h, ub.z), uh[16 + 4 * blk + 2], oh);
      oh = __builtin_elementwise_fma(__builtin_bit_cast(v2h, ub.w), uh[16 + 4 * blk + 3], oh);
    }
    v2f o = (v2f){(float)oh.x, (float)oh.y};
    v2f v = squash2(o);
    if (r == 2) {
      out[(s0 + 0) * 256 + t] = v.x;
      out[(s0 + 1) * 256 + t] = v.y;
    } else {
      v2h vh = pack2h(v.x, v.y);
      b_update2<false>(vh, uh, dc, bp0, bp1);
      __syncthreads();  // b complete before round-2 softmax; c overwrite safe
    }
  }
}

extern "C" void kernel_launch(void* const* d_in, const int* in_sizes, int n_in,
                              void* d_out, int out_size, void* d_ws, size_t ws_size,
                              hipStream_t stream) {
  const float* x = (const float*)d_in[0];
  const float* W = (const float*)d_in[1];
  _Float16* Wth = (_Float16*)d_ws;           // 128 KB: f16 W-transpose
  _Float16* xh  = (_Float16*)d_ws + 65536;   // 4 MB: f16 x

  prep_kernel<<<1280, 256, 0, stream>>>(W, x, Wth, xh);
  caps_kernel<<<8192 / S, 256, 0, stream>>>(xh, (const uint4*)Wth, (float*)d_out);
}

// Round 4
// 91.060 us; speedup vs baseline: 1.0879x; 1.0137x over previous
//
#include <hip/hip_runtime.h>
#include <hip/hip_bf16.h>

// CapsuleNet dynamic routing, fused per-sample. fp32 I/O:
// x: f32 [8192, 32, 8], W: f32 [32, 8, 256], out: f32 [8192, 16, 16].
// One block = S samples; thread t = (nc = t>>4, dc = t&15) owns column k = t.
// r15: x reads are WAVE-UNIFORM s_loads of pre-converted f16. uh packed f16
// (s,s+1) v2h; butterfly uses 32-bit cndmask selects + DPP transports.
// r16: c.uh reads as ds_read_b128 broadcasts; b_lds transposed so softmax
// row-read is ds_read_b128; butterfly b-writes 2-way (free).
// r17/r18: (256,6) revert (r16's (256,8) forced VGPR=32 -> uh spill,
// WRITE_SIZE 77.8 MB); CSTRIDE 44. Result: caps ~41 us, plateau.
// r19 (this round): S 2 -> 4. Theory: additive phase-convoy of
// VALU(~13us) + W-L1-refetch(~10us: 128KB Wth re-read per block) + DS(~7us).
// S=4 halves W traffic per sample, halves block/barrier count, doubles
// per-thread ILP (two independent packed sample-pairs). uh state doubles to
// 64 VGPR -> __launch_bounds__(256,4) (128 budget, no spill).

#define S 4

typedef float    v2f __attribute__((ext_vector_type(2)));
typedef float    v4f __attribute__((ext_vector_type(4)));
typedef _Float16 v2h __attribute__((ext_vector_type(2)));
typedef _Float16 v8h __attribute__((ext_vector_type(8)));

__device__ __forceinline__ v2h pack2h(float a, float b) {
  return __builtin_bit_cast(v2h, __builtin_amdgcn_cvt_pkrtz(a, b));  // v_cvt_pkrtz_f16_f32
}

// DPP cross-lane: value of `x` from lane (lane ^ k) within a 16-lane row.
// 0xB1 = quad_perm[1,0,3,2] (xor1)  0x4E = quad_perm[2,3,0,1] (xor2)
// 0x128 = row_ror:8 (xor8)  0x141 = row_half_mirror  0x140 = row_mirror
template <int CTRL>
__device__ __forceinline__ float dppf(float x) {
  return __builtin_bit_cast(float,
      __builtin_amdgcn_update_dpp(0, __builtin_bit_cast(int, x), CTRL, 0xF, 0xF, true));
}
template <int CTRL>
__device__ __forceinline__ v2h dpph(v2h v) {  // both samples in one DPP
  return __builtin_bit_cast(v2h,
      __builtin_amdgcn_update_dpp(0, __builtin_bit_cast(int, v), CTRL, 0xF, 0xF, true));
}
// Masked DPP keeping `old` on disabled banks (bound_ctrl=false: keep old).
template <int CTRL, int BANK>
__device__ __forceinline__ int dpp_old_i(int old, int x) {
  return __builtin_amdgcn_update_dpp(old, x, CTRL, 0xF, BANK, false);
}
// Deliver partner(lane^4)'s value of s to every lane (validated r10/r13):
// banks 0,2 (lanes 0-3,8-11): from lane+4 via row_shl:4 (0x104);
// banks 1,3 (lanes 4-7,12-15): from lane-4 via row_shr:4 (0x114).
__device__ __forceinline__ v2h xor4t_h(v2h s) {
  int si = __builtin_bit_cast(int, s);
  int ya = dpp_old_i<0x104, 0x5>(0, si);
  return __builtin_bit_cast(v2h, dpp_old_i<0x114, 0xA>(ya, si));
}

#if __has_builtin(__builtin_amdgcn_fdot2)
__device__ __forceinline__ float dot2(v2h a, v2h b, float c) {
  return __builtin_amdgcn_fdot2(a, b, c, false);  // v_dot2_f32_f16
}
#else
__device__ __forceinline__ float dot2(v2h a, v2h b, float c) {
  return fmaf((float)a.x, (float)b.x, fmaf((float)a.y, (float)b.y, c));
}
#endif

// Fused prep: blocks 0..255: W[ic][id][k](f32) -> Wth[ic][k][id](f16), NO
// permute; blocks 256..1279: x (f32) -> xh (f16), 8 elems/thread.
__global__ __launch_bounds__(256) void prep_kernel(const float* __restrict__ W,
                                                   const float* __restrict__ x,
                                                   _Float16* __restrict__ Wth,
                                                   _Float16* __restrict__ xh) {
  int bid = blockIdx.x;
  if (bid < 256) {
    int o  = bid * 256 + threadIdx.x;
    int ic = o >> 11;
    int k  = (o >> 3) & 255;
    int id = o & 7;
    Wth[o] = (_Float16)W[(ic * 8 + id) * 256 + k];
  } else {
    int tid = (bid - 256) * 256 + threadIdx.x;
    const float4* xp = (const float4*)x + tid * 2;
    float4 f0 = xp[0], f1 = xp[1];
    v2h h0 = {(_Float16)f0.x, (_Float16)f0.y};
    v2h h1 = {(_Float16)f0.z, (_Float16)f0.w};
    v2h h2 = {(_Float16)f1.x, (_Float16)f1.y};
    v2h h3 = {(_Float16)f1.z, (_Float16)f1.w};
    uint4 o;
    o.x = __builtin_bit_cast(unsigned, h0);
    o.y = __builtin_bit_cast(unsigned, h1);
    o.z = __builtin_bit_cast(unsigned, h2);
    o.w = __builtin_bit_cast(unsigned, h3);
    ((uint4*)xh)[tid] = o;
  }
}

// squash over the 16 dc lanes, both samples at once; DPP-only reduction (f32).
__device__ __forceinline__ v2f squash2(v2f o) {
  v2f s2 = o * o;
  s2.x += dppf<0xB1>(s2.x);   s2.y += dppf<0xB1>(s2.y);    // + lane^1
  s2.x += dppf<0x4E>(s2.x);   s2.y += dppf<0x4E>(s2.y);    // + lane^2
  s2.x += dppf<0x141>(s2.x);  s2.y += dppf<0x141>(s2.y);   // + lane^7
  s2.x += dppf<0x140>(s2.x);  s2.y += dppf<0x140>(s2.y);   // + lane^15
  s2 += (v2f){1e-7f, 1e-7f};
  v2f sc;
  sc.x = s2.x * __builtin_amdgcn_rsqf(s2.x) * __builtin_amdgcn_rcpf(1.f + s2.x);
  sc.y = s2.y * __builtin_amdgcn_rsqf(s2.y) * __builtin_amdgcn_rcpf(1.f + s2.y);
  return o * sc;  // sqrt(s2)/(1+s2) * o
}

// Butterfly transpose-reduction on NORMAL-order packed-f16 uh (selects are
// single 32-bit cndmasks moving both samples). Lane dc lands b[icb+dc][nc]
// (f32, transposed layout: bp* pre-offset to &b_lds[s][dc][nc], row stride
// 20 floats; icb*20 is a compile-time ds offset immediate).
// Levels 8/2/1 via DPP xor; level 4 via the masked dual-DPP transport.
template <bool ASSIGN>
__device__ __forceinline__ void b_update2(v2h vh, const v2h* uh, int dc,
                                          float* bp0, float* bp1) {
#pragma unroll
  for (int icb = 0; icb < 32; icb += 16) {
    v2h a[16];
#pragma unroll
    for (int j = 0; j < 16; ++j) a[j] = vh * uh[icb + j];  // pk_mul_f16
    v2h b8[8];
    const bool u8 = (dc & 8) != 0;
#pragma unroll
    for (int j = 0; j < 8; ++j) {
      v2h send = u8 ? a[j] : a[j + 8];
      v2h recv = dpph<0x128>(send);              // partner(lane^8)'s send
      b8[j] = (u8 ? a[j + 8] : a[j]) + recv;
    }
    v2h c4[4];
    const bool u4 = (dc & 4) != 0;
#pragma unroll
    for (int j = 0; j < 4; ++j) {
      v2h send = u4 ? b8[j] : b8[j + 4];
      v2h recv = xor4t_h(send);                  // partner(lane^4)'s send
      c4[j] = (u4 ? b8[j + 4] : b8[j]) + recv;
    }
    v2h d2[2];
    const bool u2 = (dc & 2) != 0;
#pragma unroll
    for (int j = 0; j < 2; ++j) {
      v2h send = u2 ? c4[j] : c4[j + 2];
      v2h recv = dpph<0x4E>(send);               // partner(lane^2)'s send
      d2[j] = (u2 ? c4[j + 2] : c4[j]) + recv;
    }
    const bool u1 = (dc & 1) != 0;
    v2h send = u1 ? d2[0] : d2[1];
    v2h recv = dpph<0xB1>(send);                 // partner(lane^1)'s send
    v2h e = (u1 ? d2[1] : d2[0]) + recv;
    float e0 = (float)e.x, e1 = (float)e.y;
    if (ASSIGN) { bp0[icb * 20] = e0;  bp1[icb * 20] = e1; }
    else        { bp0[icb * 20] += e0; bp1[icb * 20] += e1; }
  }
}

#define CSTRIDE 44  // v2h per c-row: 176 B rows (16B-aligned). Read side: 4
                    // nc-row b128 broadcasts start at banks (12nc+4blk)%32 ->
                    // 4 disjoint 4-bank spans. Write side: 2 lanes/bank (free).

__global__ __launch_bounds__(256, 4) void caps_kernel(const _Float16* __restrict__ xh,
                                                      const uint4* __restrict__ Wt4,
                                                      float* __restrict__ out) {
  const int t  = threadIdx.x;
  const int nc = t >> 4;
  const int dc = t & 15;
  const int s0 = blockIdx.x * S;

  // b transposed: [sample][ic 0..31][nc 0..15 padded to 20].
  // softmax reads b[ss][ic][8q..8q+7] as TWO ds_read_b128 (16B-aligned).
  __shared__ __align__(16) float b_lds[S][32][20];
  __shared__ __align__(16) v2h cAh[16 * CSTRIDE];  // c pairs, samples (0,1)
  __shared__ __align__(16) v2h cBh[16 * CSTRIDE];  // c pairs, samples (2,3)

  v2h uhA[32], uhB[32];                // packed (s0,s1) / (s2,s3)
  v2f oA = (v2f){0.f, 0.f};
  v2f oB = (v2f){0.f, 0.f};

  // ---- u_hat: wave-uniform x (s_load, free) + ONE b128 W load per ic,
  //      amortized over 4 samples ----
  const v2h* xp0 = (const v2h*)(xh + (s0 + 0) * 256);  // block-uniform -> s_load
  const v2h* xp1 = (const v2h*)(xh + (s0 + 1) * 256);
  const v2h* xp2 = (const v2h*)(xh + (s0 + 2) * 256);
  const v2h* xp3 = (const v2h*)(xh + (s0 + 3) * 256);
#pragma unroll
  for (int ic = 0; ic < 32; ++ic) {
    uint4 wv = Wt4[ic * 256 + t];  // 8 f16 weights, one coalesced dwordx4
    v2h w0 = __builtin_bit_cast(v2h, wv.x);
    v2h w1 = __builtin_bit_cast(v2h, wv.y);
    v2h w2 = __builtin_bit_cast(v2h, wv.z);
    v2h w3 = __builtin_bit_cast(v2h, wv.w);
    float a0 = dot2(xp0[ic * 4 + 3], w3, dot2(xp0[ic * 4 + 2], w2,
               dot2(xp0[ic * 4 + 1], w1, dot2(xp0[ic * 4 + 0], w0, 0.f))));
    float a1 = dot2(xp1[ic * 4 + 3], w3, dot2(xp1[ic * 4 + 2], w2,
               dot2(xp1[ic * 4 + 1], w1, dot2(xp1[ic * 4 + 0], w0, 0.f))));
    float a2 = dot2(xp2[ic * 4 + 3], w3, dot2(xp2[ic * 4 + 2], w2,
               dot2(xp2[ic * 4 + 1], w1, dot2(xp2[ic * 4 + 0], w0, 0.f))));
    float a3 = dot2(xp3[ic * 4 + 3], w3, dot2(xp3[ic * 4 + 2], w2,
               dot2(xp3[ic * 4 + 1], w1, dot2(xp3[ic * 4 + 0], w0, 0.f))));
    oA += (v2f){a0, a1};
    oB += (v2f){a2, a3};
    uhA[ic] = pack2h(a0, a1);
    uhB[ic] = pack2h(a2, a3);
  }

  float* bp0 = &b_lds[0][dc][nc];  // transposed-target bases for this thread
  float* bp1 = &b_lds[1][dc][nc];
  float* bp2 = &b_lds[2][dc][nc];
  float* bp3 = &b_lds[3][dc][nc];

  // ---- routing round 0: b = 0 => c = 1/16 ----
  {
    v2f vA = squash2(oA * (v2f){0.0625f, 0.0625f});
    v2f vB = squash2(oB * (v2f){0.0625f, 0.0625f});
    b_update2<true>(pack2h(vA.x, vA.y), uhA, dc, bp0, bp1);
    b_update2<true>(pack2h(vB.x, vB.y), uhB, dc, bp2, bp3);
  }
  __syncthreads();

  // ---- rounds 1, 2 ----
#pragma unroll
  for (int r = 1; r < 3; ++r) {
    {  // distributed softmax over nc: 256 threads. thread -> (ss, ic, half)
      const int ss  = t >> 6;         // sample 0..3 (wave-uniform)
      const int icc = (t >> 1) & 31;  // column (ic)
      const int q   = t & 1;          // nc rows 8q..8q+7
      // no max-subtraction: |b| bounded far below exp overflow; shift-invariant.
      const v4f bL = *(const v4f*)&b_lds[ss][icc][8 * q + 0];  // ds_read_b128
      const v4f bH = *(const v4f*)&b_lds[ss][icc][8 * q + 4];  // ds_read_b128
      float e0 = __expf(bL.x), e1 = __expf(bL.y), e2 = __expf(bL.z), e3 = __expf(bL.w);
      float e4 = __expf(bH.x), e5 = __expf(bH.y), e6 = __expf(bH.z), e7 = __expf(bH.w);
      float ps = ((e0 + e1) + (e2 + e3)) + ((e4 + e5) + (e6 + e7));
      ps += dppf<0xB1>(ps);  // + lane^1 (partner half) -> full 16-row sum
      float inv = __builtin_amdgcn_rcpf(ps);
      _Float16* cw = (_Float16*)(ss < 2 ? cAh : cBh) + (ss & 1);  // pair component
      cw[((8 * q + 0) * CSTRIDE + icc) * 2] = (_Float16)(e0 * inv);
      cw[((8 * q + 1) * CSTRIDE + icc) * 2] = (_Float16)(e1 * inv);
      cw[((8 * q + 2) * CSTRIDE + icc) * 2] = (_Float16)(e2 * inv);
      cw[((8 * q + 3) * CSTRIDE + icc) * 2] = (_Float16)(e3 * inv);
      cw[((8 * q + 4) * CSTRIDE + icc) * 2] = (_Float16)(e4 * inv);
      cw[((8 * q + 5) * CSTRIDE + icc) * 2] = (_Float16)(e5 * inv);
      cw[((8 * q + 6) * CSTRIDE + icc) * 2] = (_Float16)(e6 * inv);
      cw[((8 * q + 7) * CSTRIDE + icc) * 2] = (_Float16)(e7 * inv);
    }
    __syncthreads();

    // c.uh: 8 ds_read_b128 broadcasts per table (4 ic-pairs per b128).
    const v8h* crA = (const v8h*)(cAh + nc * CSTRIDE);
    const v8h* crB = (const v8h*)(cBh + nc * CSTRIDE);
    v2h ohA = (v2h){(_Float16)0.f, (_Float16)0.f};
    v2h ohB = (v2h){(_Float16)0.f, (_Float16)0.f};
#pragma unroll
    for (int blk = 0; blk < 4; ++blk) {
      uint4 ua = __builtin_bit_cast(uint4, crA[blk]);      // ic 4blk..4blk+3
      uint4 ub = __builtin_bit_cast(uint4, crA[blk + 4]);  // ic 16+4blk..
      ohA = __builtin_elementwise_fma(__builtin_bit_cast(v2h, ua.x), uhA[4 * blk + 0], ohA);
      ohA = __builtin_elementwise_fma(__builtin_bit_cast(v2h, ua.y), uhA[4 * blk + 1], ohA);
      ohA = __builtin_elementwise_fma(__builtin_bit_cast(v2h, ua.z), uhA[4 * blk + 2], ohA);
      ohA = __builtin_elementwise_fma(__builtin_bit_cast(v2h, ua.w), uhA[4 * blk + 3], ohA);
      ohA = __builtin_elementwise_fma(__builtin_bit_cast(v2h, ub.x), uhA[16 + 4 * blk + 0], ohA);
      ohA = __builtin_elementwise_fma(__builtin_bit_cast(v2h, ub.y), uhA[16 + 4 * blk + 1], ohA);
      ohA = __builtin_elementwise_fma(__builtin_bit_cast(v2h, ub.z), uhA[16 + 4 * blk + 2], ohA);
      ohA = __builtin_elementwise_fma(__builtin_bit_cast(v2h, ub.w), uhA[16 + 4 * blk + 3], ohA);
      uint4 va = __builtin_bit_cast(uint4, crB[blk]);
      uint4 vb = __builtin_bit_cast(uint4, crB[blk + 4]);
      ohB = __builtin_elementwise_fma(__builtin_bit_cast(v2h, va.x), uhB[4 * blk + 0], ohB);
      ohB = __builtin_elementwise_fma(__builtin_bit_cast(v2h, va.y), uhB[4 * blk + 1], ohB);
      ohB = __builtin_elementwise_fma(__builtin_bit_cast(v2h, va.z), uhB[4 * blk + 2], ohB);
      ohB = __builtin_elementwise_fma(__builtin_bit_cast(v2h, va.w), uhB[4 * blk + 3], ohB);
      ohB = __builtin_elementwise_fma(__builtin_bit_cast(v2h, vb.x), uhB[16 + 4 * blk + 0], ohB);
      ohB = __builtin_elementwise_fma(__builtin_bit_cast(v2h, vb.y), uhB[16 + 4 * blk + 1], ohB);
      ohB = __builtin_elementwise_fma(__builtin_bit_cast(v2h, vb.z), uhB[16 + 4 * blk + 2], ohB);
      ohB = __builtin_elementwise_fma(__builtin_bit_cast(v2h, vb.w), uhB[16 + 4 * blk + 3], ohB);
    }
    v2f vA = squash2((v2f){(float)ohA.x, (float)ohA.y});
    v2f vB = squash2((v2f){(float)ohB.x, (float)ohB.y});
    if (r == 2) {
      out[(s0 + 0) * 256 + t] = vA.x;
      out[(s0 + 1) * 256 + t] = vA.y;
      out[(s0 + 2) * 256 + t] = vB.x;
      out[(s0 + 3) * 256 + t] = vB.y;
    } else {
      b_update2<false>(pack2h(vA.x, vA.y), uhA, dc, bp0, bp1);
      b_update2<false>(pack2h(vB.x, vB.y), uhB, dc, bp2, bp3);
      __syncthreads();  // b complete before round-2 softmax; c overwrite safe
    }
  }
}

extern "C" void kernel_launch(void* const* d_in, const int* in_sizes, int n_in,
                              void* d_out, int out_size, void* d_ws, size_t ws_size,
                              hipStream_t stream) {
  const float* x = (const float*)d_in[0];
  const float* W = (const float*)d_in[1];
  _Float16* Wth = (_Float16*)d_ws;           // 128 KB: f16 W-transpose
  _Float16* xh  = (_Float16*)d_ws + 65536;   // 4 MB: f16 x

  prep_kernel<<<1280, 256, 0, stream>>>(W, x, Wth, xh);
  caps_kernel<<<8192 / S, 256, 0, stream>>>(xh, (const uint4*)Wth, (float*)d_out);
}